// Round 2
// baseline (1081.455 us; speedup 1.0000x reference)
//
#include <hip/hip_runtime.h>

#define NN 100000
#define NE 5000000
#define NB 16
#define NLAYER 4
#define SCAN_BLK 512
#define NSCAN ((NN + SCAN_BLK - 1) / SCAN_BLK)   // 196

// h[n*16+b] = x[n*16+b] * tw[ct[n]] + tb[ct[n]]
__global__ void type_affine(const float* __restrict__ x,
                            const float* __restrict__ tw,
                            const float* __restrict__ tb,
                            const int* __restrict__ ct,
                            float* __restrict__ h) {
    int idx = blockIdx.x * blockDim.x + threadIdx.x;
    if (idx >= NN * NB) return;
    int n = idx >> 4;
    int t = ct[n];
    h[idx] = x[idx] * tw[t] + tb[t];
}

// count edges per destination row
__global__ void row_histogram(const int* __restrict__ rows, int* __restrict__ cnt) {
    int e = blockIdx.x * blockDim.x + threadIdx.x;
    if (e >= NE) return;
    atomicAdd(&cnt[rows[e]], 1);
}

// block-level exclusive scan of cnt -> row_start (within-block), block sums -> bsum
__global__ void scan_blocks(const int* __restrict__ cnt,
                            int* __restrict__ excl, int* __restrict__ bsum) {
    __shared__ int s[SCAN_BLK];
    int gid = blockIdx.x * SCAN_BLK + threadIdx.x;
    int v = (gid < NN) ? cnt[gid] : 0;
    s[threadIdx.x] = v;
    __syncthreads();
    for (int off = 1; off < SCAN_BLK; off <<= 1) {
        int t = (threadIdx.x >= off) ? s[threadIdx.x - off] : 0;
        __syncthreads();
        s[threadIdx.x] += t;
        __syncthreads();
    }
    if (gid < NN) excl[gid] = s[threadIdx.x] - v;   // exclusive within block
    if (threadIdx.x == SCAN_BLK - 1) bsum[blockIdx.x] = s[SCAN_BLK - 1];
}

// serial scan of the 196 block sums (tiny)
__global__ void scan_bsums(int* __restrict__ bsum) {
    if (threadIdx.x == 0 && blockIdx.x == 0) {
        int run = 0;
        for (int i = 0; i < NSCAN; ++i) { int t = bsum[i]; bsum[i] = run; run += t; }
    }
}

// add block offsets; produce row_start (NN+1) and a scatter cursor copy
__global__ void scan_finalize(int* __restrict__ excl, const int* __restrict__ bsum,
                              int* __restrict__ row_start, int* __restrict__ cursor) {
    int gid = blockIdx.x * blockDim.x + threadIdx.x;
    if (gid < NN) {
        int v = excl[gid] + bsum[gid >> 9];   // 512 = 1<<9
        row_start[gid] = v;
        cursor[gid] = v;
    }
    if (gid == 0) row_start[NN] = NE;
}

// counting-sort scatter: packed[pos] = (col, w_bits)
__global__ void scatter_edges(const int* __restrict__ rows, const int* __restrict__ cols,
                              const float* __restrict__ w,
                              int* __restrict__ cursor, int2* __restrict__ packed) {
    int e = blockIdx.x * blockDim.x + threadIdx.x;
    if (e >= NE) return;
    int r = rows[e];
    int pos = atomicAdd(&cursor[r], 1);
    packed[pos] = make_int2(cols[e], __float_as_int(w[e]));
}

// one wave per row: 4 edge-groups x 16 batch lanes, register accumulate,
// shfl_xor reduce, one coalesced 64B store. No atomics.
__global__ void spmm_csr(const int* __restrict__ row_start,
                         const int2* __restrict__ packed,
                         const float* __restrict__ h_in,
                         float* __restrict__ h_out) {
    int wid = (blockIdx.x * blockDim.x + threadIdx.x) >> 6;   // row id
    if (wid >= NN) return;
    int lane = threadIdx.x & 63;
    int b = lane & 15;
    int g = lane >> 4;          // 0..3
    int s = row_start[wid];
    int e = row_start[wid + 1];
    float acc = 0.f;
    for (int i = s + g; i < e; i += 4) {
        int2 cw = packed[i];                       // broadcast within 16-lane group
        acc = fmaf(__int_as_float(cw.y), h_in[cw.x * NB + b], acc);
    }
    acc += __shfl_xor(acc, 16);
    acc += __shfl_xor(acc, 32);
    if (g == 0) h_out[wid * NB + b] = acc;         // every row written -> no memset
}

// out[b] = sum_d dm_vals[d]*fc_w[d]*h[dm_cols[d]*16+b] + fc_b
__global__ void final_fc(const float* __restrict__ dmv,
                         const int* __restrict__ dmc,
                         const float* __restrict__ fcw,
                         const float* __restrict__ fcb,
                         const float* __restrict__ h,
                         float* __restrict__ out) {
    __shared__ float red[NB];
    int t = threadIdx.x;  // 512 threads, one per decision neuron
    if (t < NB) red[t] = 0.f;
    __syncthreads();
    float wd = dmv[t] * fcw[t];
    int c = dmc[t];
    for (int b = 0; b < NB; ++b) {
        float v = wd * h[c * NB + b];
        for (int off = 32; off; off >>= 1) v += __shfl_down(v, off);
        if ((t & 63) == 0) atomicAdd(&red[b], v);
    }
    __syncthreads();
    if (t < NB) out[t] = red[t] + fcb[0];
}

extern "C" void kernel_launch(void* const* d_in, const int* in_sizes, int n_in,
                              void* d_out, int out_size, void* d_ws, size_t ws_size,
                              hipStream_t stream) {
    const float* x   = (const float*)d_in[0];
    const float* tw  = (const float*)d_in[1];
    const float* tb  = (const float*)d_in[2];
    const float* ew  = (const float*)d_in[3];
    const float* dmv = (const float*)d_in[4];
    const float* fcw = (const float*)d_in[5];
    const float* fcb = (const float*)d_in[6];
    const int* ct  = (const int*)d_in[7];
    const int* er  = (const int*)d_in[8];
    const int* ec  = (const int*)d_in[9];
    const int* dmc = (const int*)d_in[10];
    float* out = (float*)d_out;

    // workspace layout (bytes, 8B-aligned where needed)
    char* ws = (char*)d_ws;
    float* h0        = (float*)ws;                       ws += (size_t)NN * NB * 4;
    float* h1        = (float*)ws;                       ws += (size_t)NN * NB * 4;
    int*   cnt       = (int*)ws;                         ws += (size_t)NN * 4;
    int*   row_start = (int*)ws;                         ws += (size_t)(NN + 1) * 4;
    int*   cursor    = (int*)ws;                         ws += (size_t)NN * 4;
    int*   bsum      = (int*)ws;                         ws += 256 * 4;
    ws = (char*)(((uintptr_t)ws + 7) & ~(uintptr_t)7);
    int2*  packed    = (int2*)ws;                        // NE * 8B = 40MB

    // --- build CSR (each call; deterministic up to float-order jitter) ---
    hipMemsetAsync(cnt, 0, (size_t)NN * 4, stream);
    row_histogram<<<(NE + 255) / 256, 256, 0, stream>>>(er, cnt);
    scan_blocks<<<NSCAN, SCAN_BLK, 0, stream>>>(cnt, row_start, bsum);
    scan_bsums<<<1, 64, 0, stream>>>(bsum);
    scan_finalize<<<(NN + 255) / 256, 256, 0, stream>>>(row_start, bsum, row_start, cursor);
    scatter_edges<<<(NE + 255) / 256, 256, 0, stream>>>(er, ec, ew, cursor, packed);

    // --- h0 = per-type affine ---
    type_affine<<<(NN * NB + 255) / 256, 256, 0, stream>>>(x, tw, tb, ct, h0);

    // --- 4 x SpMM, atomic-free ---
    float* cur = h0;
    float* nxt = h1;
    for (int l = 0; l < NLAYER; ++l) {
        spmm_csr<<<(NN * 64 + 255) / 256, 256, 0, stream>>>(row_start, packed, cur, nxt);
        float* tmp = cur; cur = nxt; nxt = tmp;
    }

    final_fc<<<1, 512, 0, stream>>>(dmv, dmc, fcw, fcb, cur, out);
}